// Round 2
// baseline (431.787 us; speedup 1.0000x reference)
//
#include <hip/hip_runtime.h>
#include <stdint.h>

// ---------------------------------------------------------------------------
// AvgClicksPoolingInitializer  (B=8, I=16, C=256)
// Levels: L=0..3  w=128>>L, P=w*w, k=4<<L (scribble 512 / w)
// Bilinear half-pixel downsample 512->w lands exactly between two pixels in
// each dim => m[y][x] = 0.25*(S[r0][c0]+S[r0][c1]+S[r1][c0]+S[r1][c1]),
// r0 = k*y + k/2 - 1, c0 = k*x + k/2 - 1.   sel = (m > 0.5)  <=>  sum4 > 2.0
// ---------------------------------------------------------------------------

#define NI 16
#define NB 8
#define NC 256
#define PTOT 21760   // 16384+4096+1024+256

__device__ __forceinline__ int level_off(int L) {
    return (L == 0) ? 0 : (L == 1) ? 16384 : (L == 2) ? 20480 : 21504;
}

__device__ __forceinline__ unsigned int ordered_bits(float v) {
    unsigned int u = __float_as_uint(v);
    return u ^ ((u >> 31) ? 0xFFFFFFFFu : 0x80000000u);
}

// ---------------------------------------------------------------------------
// Kernel A (fast path): pure streaming — no shuffles, no atomics, no LDS.
// Writes per-pixel 16-bit sel mask and per-(b,i,p) resized value v.
// ---------------------------------------------------------------------------
__global__ __launch_bounds__(256) void mask_kernel(
        const float* __restrict__ scr,          // (8,16,512,512)
        unsigned short* __restrict__ selmask,   // (8, PTOT)
        float* __restrict__ vv) {               // (8,16, PTOT)
    const int L = blockIdx.z, b = blockIdx.y;
    const int wl2 = 7 - L;
    const int w = 1 << wl2;
    const int P = 1 << (2 * wl2);
    const int k = 4 << L;
    const int p = blockIdx.x * 256 + threadIdx.x;
    if (p >= P) return;
    const int y = p >> wl2, x = p & (w - 1);
    const int r0 = k * y + (k >> 1) - 1;
    const int c0 = k * x + (k >> 1) - 1;
    const float* Sb = scr + (size_t)b * NI * 262144;
    const int off = level_off(L);

    unsigned int mask = 0;
#pragma unroll
    for (int i = 0; i < NI; ++i) {
        const float* Si = Sb + (size_t)i * 262144 + r0 * 512 + c0;
        float v;
        if (k == 4) {
            // c0 = 4x+1: aligned float4 at 4x covers cols {4x..4x+3}; need .y,.z
            const float4 t0 = *(const float4*)(Si - 1);
            const float4 t1 = *(const float4*)(Si - 1 + 512);
            v = (t0.y + t0.z) + (t1.y + t1.z);
        } else {
            v = (Si[0] + Si[1]) + (Si[512] + Si[513]);
        }
        mask |= (v > 2.0f) ? (1u << i) : 0u;
        vv[(size_t)(b * NI + i) * PTOT + off + p] = v;     // coalesced per i
    }
    selmask[(size_t)b * PTOT + off + p] = (unsigned short)mask;
}

// ---------------------------------------------------------------------------
// Kernel A2 (fast path): per (L,b,i) block — count + first-index argmax over P
// ---------------------------------------------------------------------------
__global__ __launch_bounds__(256) void argmax_kernel(
        const float* __restrict__ vv,
        unsigned int* __restrict__ amaxp,       // (4,8,16) pixel index
        unsigned int* __restrict__ cntw) {      // (4,8,16)
    const int g = blockIdx.x;                   // 512 groups
    const int L = g >> 7, b = (g >> 4) & 7, i = g & 15;
    const int P = 16384 >> (2 * L);
    const float* base = vv + (size_t)(b * NI + i) * PTOT + level_off(L);
    const int t = threadIdx.x;

    unsigned int cnt = 0;
    unsigned long long key = 0ull;              // every thread has >=1 elem (P>=256)
    for (int p = t; p < P; p += 256) {
        const float v = base[p];
        cnt += (v > 2.0f) ? 1u : 0u;
        const unsigned long long kk =
            ((unsigned long long)ordered_bits(v) << 32)
          | (unsigned long long)(0xFFFFFFFFu - (unsigned int)p);
        if (kk > key) key = kk;                 // key starts at 0; ordered_bits>=2^31 for v>=0... safe: first kk always > 0
    }

    __shared__ unsigned long long sk[256];
    __shared__ unsigned int sc[256];
    sk[t] = key; sc[t] = cnt;
    __syncthreads();
#pragma unroll
    for (int s = 128; s > 0; s >>= 1) {
        if (t < s) {
            if (sk[t + s] > sk[t]) sk[t] = sk[t + s];
            sc[t] += sc[t + s];
        }
        __syncthreads();
    }
    if (t == 0) {
        amaxp[g] = 0xFFFFFFFFu - (unsigned int)(sk[0] & 0xFFFFFFFFull);
        cntw[g] = sc[0];
    }
}

// ---------------------------------------------------------------------------
// Fallback kernel A (small ws): old shuffle+atomic argmax path
// ---------------------------------------------------------------------------
__device__ __forceinline__ unsigned long long shfl_down_u64(unsigned long long v, int off) {
    unsigned int lo = (unsigned int)v;
    unsigned int hi = (unsigned int)(v >> 32);
    lo = __shfl_down(lo, off, 64);
    hi = __shfl_down(hi, off, 64);
    return ((unsigned long long)hi << 32) | lo;
}

__global__ __launch_bounds__(256) void mask_kernel_small(
        const float* __restrict__ scr,
        unsigned short* __restrict__ selmask,
        unsigned long long* __restrict__ keyw,
        unsigned int* __restrict__ cntw) {
    const int L = blockIdx.z, b = blockIdx.y;
    const int wl2 = 7 - L;
    const int w = 1 << wl2;
    const int P = 1 << (2 * wl2);
    const int k = 4 << L;
    const int p = blockIdx.x * 256 + threadIdx.x;
    if (p >= P) return;
    const int y = p >> wl2, x = p & (w - 1);
    const int r0 = k * y + (k >> 1) - 1;
    const int c0 = k * x + (k >> 1) - 1;
    const float* Sb = scr + (size_t)b * NI * 262144;
    const int lane = threadIdx.x & 63, wv = threadIdx.x >> 6;

    __shared__ unsigned long long skey[4][NI];
    __shared__ unsigned int scnt[4][NI];

    unsigned int mask = 0;
#pragma unroll
    for (int i = 0; i < NI; ++i) {
        const float* Si = Sb + (size_t)i * 262144 + r0 * 512 + c0;
        float v;
        if (k == 4) {
            const float4 t0 = *(const float4*)(Si - 1);
            const float4 t1 = *(const float4*)(Si - 1 + 512);
            v = (t0.y + t0.z) + (t1.y + t1.z);
        } else {
            v = (Si[0] + Si[1]) + (Si[512] + Si[513]);
        }
        const bool sel = v > 2.0f;
        mask |= sel ? (1u << i) : 0u;
        unsigned long long key = ((unsigned long long)ordered_bits(v) << 32)
                               | (unsigned long long)(0xFFFFFFFFu - (unsigned int)p);
#pragma unroll
        for (int off = 32; off > 0; off >>= 1) {
            unsigned long long o = shfl_down_u64(key, off);
            if (o > key) key = o;
        }
        unsigned long long bal = __ballot(sel);
        if (lane == 0) {
            skey[wv][i] = key;
            scnt[wv][i] = (unsigned int)__popcll(bal);
        }
    }
    selmask[(size_t)b * PTOT + level_off(L) + p] = (unsigned short)mask;

    __syncthreads();
    if (threadIdx.x < NI) {
        const int i = threadIdx.x;
        unsigned long long kk = skey[0][i];
        unsigned int cc = scnt[0][i];
#pragma unroll
        for (int wq = 1; wq < 4; ++wq) {
            if (skey[wq][i] > kk) kk = skey[wq][i];
            cc += scnt[wq][i];
        }
        atomicMax(&keyw[(L * NB + b) * NI + i], kk);
        atomicAdd(&cntw[(L * NB + b) * NI + i], cc);
    }
}

__global__ void key_to_idx(const unsigned long long* __restrict__ keyw,
                           unsigned int* __restrict__ amaxp) {
    const int g = blockIdx.x * 64 + threadIdx.x;
    if (g < 512) amaxp[g] = 0xFFFFFFFFu - (unsigned int)(keyw[g] & 0xFFFFFFFFull);
}

// ---------------------------------------------------------------------------
// Kernel B: s[L][b][i][c] = sum_p bit(i,p) * f[b][c][p]
// one wave per (b, c, L); float4 feature loads + ushort4 mask loads
// ---------------------------------------------------------------------------
__global__ __launch_bounds__(256) void pool_kernel(
        const float* __restrict__ f0, const float* __restrict__ f1,
        const float* __restrict__ f2, const float* __restrict__ f3,
        const unsigned short* __restrict__ selmask,
        float* __restrict__ sw) {               // (4,8,16,256)
    const int L = blockIdx.z, b = blockIdx.y;
    const int wl2 = 7 - L;
    const int P = 1 << (2 * wl2);
    const int lane = threadIdx.x & 63, wv = threadIdx.x >> 6;
    const int c = blockIdx.x * 4 + wv;
    const float* fL = (L == 0) ? f0 : (L == 1) ? f1 : (L == 2) ? f2 : f3;
    const float4* frow = (const float4*)(fL + (size_t)(b * NC + c) * P);
    const ushort4* srow = (const ushort4*)(selmask + (size_t)b * PTOT + level_off(L));

    float acc[NI];
#pragma unroll
    for (int i = 0; i < NI; ++i) acc[i] = 0.0f;

    const int iters = P >> 8;
    for (int it = 0; it < iters; ++it) {
        const int e = it * 64 + lane;
        const float4 fv = frow[e];
        const ushort4 mv = srow[e];
        {
            const float f = fv.x; const unsigned int m = mv.x;
#pragma unroll
            for (int i = 0; i < NI; ++i) acc[i] = fmaf((float)((m >> i) & 1u), f, acc[i]);
        }
        {
            const float f = fv.y; const unsigned int m = mv.y;
#pragma unroll
            for (int i = 0; i < NI; ++i) acc[i] = fmaf((float)((m >> i) & 1u), f, acc[i]);
        }
        {
            const float f = fv.z; const unsigned int m = mv.z;
#pragma unroll
            for (int i = 0; i < NI; ++i) acc[i] = fmaf((float)((m >> i) & 1u), f, acc[i]);
        }
        {
            const float f = fv.w; const unsigned int m = mv.w;
#pragma unroll
            for (int i = 0; i < NI; ++i) acc[i] = fmaf((float)((m >> i) & 1u), f, acc[i]);
        }
    }

#pragma unroll
    for (int i = 0; i < NI; ++i) {
        float a = acc[i];
#pragma unroll
        for (int off = 32; off > 0; off >>= 1) a += __shfl_down(a, off, 64);
        if (lane == 0) sw[((size_t)(L * NB + b) * NI + i) * NC + c] = a;
    }
}

// ---------------------------------------------------------------------------
// Kernel C: out[b][i][c] = 0.25 * sum_L (cnt>0 ? s/cnt : f[b][c][argmax])
// ---------------------------------------------------------------------------
__global__ __launch_bounds__(256) void final_kernel(
        const float* __restrict__ f0, const float* __restrict__ f1,
        const float* __restrict__ f2, const float* __restrict__ f3,
        const float* __restrict__ sw,
        const unsigned int* __restrict__ cntw,
        const unsigned int* __restrict__ amaxp,
        float* __restrict__ out) {
    const int n = blockIdx.x * 256 + threadIdx.x;   // 32768 total
    const int c = n & 255;
    const int bi = n >> 8;
    const int i = bi & (NI - 1);
    const int b = bi >> 4;
    float acc = 0.0f;
#pragma unroll
    for (int L = 0; L < 4; ++L) {
        const int g = (L * NB + b) * NI + i;
        const unsigned int cc = cntw[g];
        if (cc > 0) {
            acc += sw[(size_t)g * NC + c] / (float)cc;
        } else {
            const unsigned int p = amaxp[g];
            const float* fL = (L == 0) ? f0 : (L == 1) ? f1 : (L == 2) ? f2 : f3;
            const int P = 16384 >> (2 * L);
            acc += fL[(size_t)(b * NC + c) * P + p];
        }
    }
    out[n] = acc * 0.25f;
}

extern "C" void kernel_launch(void* const* d_in, const int* in_sizes, int n_in,
                              void* d_out, int out_size, void* d_ws, size_t ws_size,
                              hipStream_t stream) {
    (void)in_sizes; (void)n_in; (void)out_size;
    const float* f0  = (const float*)d_in[0];   // (8,256,128,128)
    const float* f1  = (const float*)d_in[1];   // (8,256,64,64)
    const float* f2  = (const float*)d_in[2];   // (8,256,32,32)
    const float* f3  = (const float*)d_in[3];   // (8,256,16,16)
    const float* scr = (const float*)d_in[4];   // (8,16,512,512)
    float* out = (float*)d_out;                 // (8,16,256) fp32

    char* ws = (char*)d_ws;

    const size_t VV_SZ   = (size_t)NB * NI * PTOT * 4;      // 11,141,120
    const size_t SW_SZ   = (size_t)4 * NB * NI * NC * 4;    //    524,288
    const size_t SEL_SZ  = (size_t)NB * PTOT * 2;           //    348,160
    const size_t CNT_SZ  = 512 * 4;
    const size_t IDX_SZ  = 512 * 4;
    const size_t KEY_SZ  = 512 * 8;

    if (ws_size >= VV_SZ + SW_SZ + SEL_SZ + CNT_SZ + IDX_SZ) {
        // ---- fast path ----
        float*          vvw  = (float*)ws;
        float*          sww  = (float*)(ws + VV_SZ);
        unsigned short* selm = (unsigned short*)(ws + VV_SZ + SW_SZ);
        unsigned int*   cntw = (unsigned int*)(ws + VV_SZ + SW_SZ + SEL_SZ);
        unsigned int*   idxw = (unsigned int*)(ws + VV_SZ + SW_SZ + SEL_SZ + CNT_SZ);

        dim3 gA(64, NB, 4);
        mask_kernel<<<gA, 256, 0, stream>>>(scr, selm, vvw);

        argmax_kernel<<<512, 256, 0, stream>>>(vvw, idxw, cntw);

        dim3 gB(NC / 4, NB, 4);
        pool_kernel<<<gB, 256, 0, stream>>>(f0, f1, f2, f3, selm, sww);

        final_kernel<<<128, 256, 0, stream>>>(f0, f1, f2, f3, sww, cntw, idxw, out);
    } else {
        // ---- fallback: small workspace, old shuffle/atomic argmax ----
        float*              sww  = (float*)ws;
        unsigned short*     selm = (unsigned short*)(ws + SW_SZ);
        unsigned int*       cntw = (unsigned int*)(ws + SW_SZ + SEL_SZ);
        unsigned int*       idxw = (unsigned int*)(ws + SW_SZ + SEL_SZ + CNT_SZ);
        unsigned long long* keyw = (unsigned long long*)(ws + SW_SZ + SEL_SZ + CNT_SZ + IDX_SZ);

        hipMemsetAsync(cntw, 0, CNT_SZ + IDX_SZ + KEY_SZ, stream);

        dim3 gA(64, NB, 4);
        mask_kernel_small<<<gA, 256, 0, stream>>>(scr, selm, keyw, cntw);
        key_to_idx<<<8, 64, 0, stream>>>(keyw, idxw);

        dim3 gB(NC / 4, NB, 4);
        pool_kernel<<<gB, 256, 0, stream>>>(f0, f1, f2, f3, selm, sww);

        final_kernel<<<128, 256, 0, stream>>>(f0, f1, f2, f3, sww, cntw, idxw, out);
    }
}

// Round 3
// 342.713 us; speedup vs baseline: 1.2599x; 1.2599x over previous
//
#include <hip/hip_runtime.h>
#include <stdint.h>

// ---------------------------------------------------------------------------
// AvgClicksPoolingInitializer  (B=8, I=16, C=256)
// Levels: L=0..3  w=128>>L, P=w*w, k=4<<L (scribble 512 / w)
// Bilinear half-pixel downsample 512->w lands exactly between two pixels in
// each dim => m[y][x] = 0.25*(S[r0][c0]+S[r0][c1]+S[r1][c0]+S[r1][c1]),
// r0 = k*y + k/2 - 1, c0 = k*x + k/2 - 1.   sel = (m > 0.5)  <=>  sum4 > 2.0
// ---------------------------------------------------------------------------

#define NI 16
#define NB 8
#define NC 256
#define PTOT 21760   // 16384+4096+1024+256

typedef __attribute__((ext_vector_type(8))) short bf16x8;
typedef __attribute__((ext_vector_type(4))) float f32x4;

__device__ __forceinline__ int level_off(int L) {
    return (L == 0) ? 0 : (L == 1) ? 16384 : (L == 2) ? 20480 : 21504;
}

__device__ __forceinline__ unsigned int ordered_bits(float v) {
    unsigned int u = __float_as_uint(v);
    return u ^ ((u >> 31) ? 0xFFFFFFFFu : 0x80000000u);
}

__device__ __forceinline__ unsigned short f2bf(float x) {   // RNE, finite inputs
    unsigned int u = __float_as_uint(x);
    u += 0x7FFFu + ((u >> 16) & 1u);
    return (unsigned short)(u >> 16);
}

// ---------------------------------------------------------------------------
// Kernel A: 4 waves/block = 4 instance-groups; each thread: 4 instances,
// ALL loads batched into registers (one latency round-trip per thread).
// grid (256, 8, 4): blockIdx.x over 64-pixel chunks, early-exit past P/64.
// ---------------------------------------------------------------------------
__global__ __launch_bounds__(256) void mask_kernel(
        const float* __restrict__ scr,          // (8,16,512,512)
        unsigned short* __restrict__ selmask,   // (8, PTOT)
        float* __restrict__ vv) {               // (8,16, PTOT)
    const int L = blockIdx.z, b = blockIdx.y;
    const int wl2 = 7 - L;
    const int w = 1 << wl2;
    const int P = 1 << (2 * wl2);
    const int k = 4 << L;
    if (blockIdx.x >= (P >> 6)) return;         // uniform block exit (before barrier)
    const int tx = threadIdx.x & 63;
    const int g  = threadIdx.x >> 6;            // instance group 0..3
    const int p = blockIdx.x * 64 + tx;
    const int y = p >> wl2, x = p & (w - 1);
    const int r0 = k * y + (k >> 1) - 1;
    const int c0 = k * x + (k >> 1) - 1;
    const int off = level_off(L);
    const float* Sg = scr + (size_t)(b * NI + g * 4) * 262144 + r0 * 512 + c0;

    float v[4];
    if (k == 4) {
        // c0 = 4x+1: aligned float4 at col 4x; need .y,.z
        float4 t0[4], t1[4];
#pragma unroll
        for (int j = 0; j < 4; ++j) {
            const float* Si = Sg + (size_t)j * 262144;
            t0[j] = *(const float4*)(Si - 1);
            t1[j] = *(const float4*)(Si - 1 + 512);
        }
#pragma unroll
        for (int j = 0; j < 4; ++j)
            v[j] = (t0[j].y + t0[j].z) + (t1[j].y + t1[j].z);
    } else {
        float a0[4], a1[4], a2[4], a3[4];
#pragma unroll
        for (int j = 0; j < 4; ++j) {
            const float* Si = Sg + (size_t)j * 262144;
            a0[j] = Si[0]; a1[j] = Si[1]; a2[j] = Si[512]; a3[j] = Si[513];
        }
#pragma unroll
        for (int j = 0; j < 4; ++j)
            v[j] = (a0[j] + a1[j]) + (a2[j] + a3[j]);
    }

    unsigned int nib = 0;
#pragma unroll
    for (int j = 0; j < 4; ++j) {
        nib |= (v[j] > 2.0f) ? (1u << j) : 0u;
        vv[(size_t)(b * NI + g * 4 + j) * PTOT + off + p] = v[j];
    }

    __shared__ unsigned int sh[4][64];
    sh[g][tx] = nib << (g * 4);
    __syncthreads();
    if (threadIdx.x < 64) {
        selmask[(size_t)b * PTOT + off + blockIdx.x * 64 + threadIdx.x] =
            (unsigned short)(sh[0][threadIdx.x] | sh[1][threadIdx.x] |
                             sh[2][threadIdx.x] | sh[3][threadIdx.x]);
    }
}

// ---------------------------------------------------------------------------
// Kernel A2: per (L,b,i) block — count + first-index argmax over P
// ---------------------------------------------------------------------------
__global__ __launch_bounds__(256) void argmax_kernel(
        const float* __restrict__ vv,
        unsigned int* __restrict__ amaxp,       // (4,8,16)
        unsigned int* __restrict__ cntw) {      // (4,8,16)
    const int g = blockIdx.x;                   // 512 groups
    const int L = g >> 7, b = (g >> 4) & 7, i = g & 15;
    const int P = 16384 >> (2 * L);
    const float* base = vv + (size_t)(b * NI + i) * PTOT + level_off(L);
    const int t = threadIdx.x;

    unsigned int cnt = 0;
    unsigned long long key = 0ull;
    for (int p = t; p < P; p += 256) {
        const float v = base[p];
        cnt += (v > 2.0f) ? 1u : 0u;
        const unsigned long long kk =
            ((unsigned long long)ordered_bits(v) << 32)
          | (unsigned long long)(0xFFFFFFFFu - (unsigned int)p);
        if (kk > key) key = kk;
    }

    __shared__ unsigned long long sk[256];
    __shared__ unsigned int sc[256];
    sk[t] = key; sc[t] = cnt;
    __syncthreads();
#pragma unroll
    for (int s = 128; s > 0; s >>= 1) {
        if (t < s) {
            if (sk[t + s] > sk[t]) sk[t] = sk[t + s];
            sc[t] += sc[t + s];
        }
        __syncthreads();
    }
    if (t == 0) {
        amaxp[g] = 0xFFFFFFFFu - (unsigned int)(sk[0] & 0xFFFFFFFFull);
        cntw[g] = sc[0];
    }
}

// ---------------------------------------------------------------------------
// Kernel B: MFMA pooling.  S[i,c] = sum_p sel[i,p]*f[c,p]  per (L,b).
// M=16 instances, N=16 c per wave (64 c per block), K = p in BK=128 chunks,
// K-split x8 across blocks, fp32 atomicAdd into zeroed sw.
// A-frag: A[m=lane&15][k=quad*8+j]; B-frag: B[k=quad*8+j][n=lane&15]
// -> B LDS layout [c][p] == f's natural layout (no transpose).
// ---------------------------------------------------------------------------
#define BK 128
#define BKP 136   // +8 bf16 pad: breaks 16-way LDS bank conflict on frag reads

__global__ __launch_bounds__(256) void pool_mfma(
        const float* __restrict__ f0, const float* __restrict__ f1,
        const float* __restrict__ f2, const float* __restrict__ f3,
        const unsigned short* __restrict__ selmask,
        float* __restrict__ sw) {               // (4,8,16,256) zero-init
    const int L = blockIdx.z, b = blockIdx.y;
    const int ct = blockIdx.x & 3;              // c-tile of 64
    const int split = blockIdx.x >> 2;          // 0..7
    const int P = 16384 >> (2 * L);
    const int chunks = P >> 7;                  // 128,32,8,2
    const float* fL = (L == 0) ? f0 : (L == 1) ? f1 : (L == 2) ? f2 : f3;
    const float* fbase = fL + (size_t)(b * NC + ct * 64) * P;
    const unsigned short* selb = selmask + (size_t)b * PTOT + level_off(L);

    __shared__ short As[16 * BKP];              //  4352 B
    __shared__ short Bs[64 * BKP];              // 17408 B

    const int t = threadIdx.x;
    const int lane = t & 63, wv = t >> 6;
    const int n = lane & 15, quad = lane >> 4;

    // staging roles
    const int br   = t >> 2;                    // B row (c in tile), 0..63
    const int bseg = (t & 3) * 32;              // p segment
    const int ai   = t & 15;                    // A row (instance)
    const int asub = (t >> 4) * 8;              // A col base

    f32x4 acc = {0.f, 0.f, 0.f, 0.f};

    for (int chunk = split; chunk < chunks; chunk += 8) {
        const int p0 = chunk * BK;
        // ---- stage B: 64 c-rows x 128 p fp32 -> bf16 (8 float4 / thread)
        const float4* src = (const float4*)(fbase + (size_t)br * P + p0 + bseg);
#pragma unroll
        for (int j = 0; j < 8; j += 2) {
            const float4 u0 = src[j];
            const float4 u1 = src[j + 1];
            bf16x8 hv;
            hv[0] = (short)f2bf(u0.x); hv[1] = (short)f2bf(u0.y);
            hv[2] = (short)f2bf(u0.z); hv[3] = (short)f2bf(u0.w);
            hv[4] = (short)f2bf(u1.x); hv[5] = (short)f2bf(u1.y);
            hv[6] = (short)f2bf(u1.z); hv[7] = (short)f2bf(u1.w);
            *(bf16x8*)&Bs[br * BKP + bseg + j * 4] = hv;
        }
        // ---- stage A: selmask bits -> bf16 0/1, 8 k's per thread
        {
            const uint4 smv = *(const uint4*)(selb + p0 + asub);
            unsigned int uu[4] = {smv.x, smv.y, smv.z, smv.w};
            bf16x8 ha;
#pragma unroll
            for (int j = 0; j < 4; ++j) {
                const unsigned int lo = uu[j] & 0xFFFFu, hi = uu[j] >> 16;
                ha[2 * j]     = ((lo >> ai) & 1u) ? (short)0x3F80 : (short)0;
                ha[2 * j + 1] = ((hi >> ai) & 1u) ? (short)0x3F80 : (short)0;
            }
            *(bf16x8*)&As[ai * BKP + asub] = ha;
        }
        __syncthreads();
        // ---- 4 MFMA k-steps (K=32 each)
        const int crow = wv * 16 + n;
#pragma unroll
        for (int ks = 0; ks < 4; ++ks) {
            const int k0 = ks * 32 + quad * 8;
            const bf16x8 av = *(const bf16x8*)&As[n * BKP + k0];
            const bf16x8 bv = *(const bf16x8*)&Bs[crow * BKP + k0];
            acc = __builtin_amdgcn_mfma_f32_16x16x32_bf16(av, bv, acc, 0, 0, 0);
        }
        __syncthreads();
    }

    // ---- epilogue: D[m=i][n=c]: col=lane&15, row=quad*4+r
    const int cg = ct * 64 + wv * 16 + n;
#pragma unroll
    for (int r = 0; r < 4; ++r) {
        const int i = quad * 4 + r;
        atomicAdd(&sw[(size_t)((L * NB + b) * NI + i) * NC + cg], acc[r]);
    }
}

// ---------------------------------------------------------------------------
// Fallback kernels (small workspace path)
// ---------------------------------------------------------------------------
__device__ __forceinline__ unsigned long long shfl_down_u64(unsigned long long v, int off) {
    unsigned int lo = (unsigned int)v;
    unsigned int hi = (unsigned int)(v >> 32);
    lo = __shfl_down(lo, off, 64);
    hi = __shfl_down(hi, off, 64);
    return ((unsigned long long)hi << 32) | lo;
}

__global__ __launch_bounds__(256) void mask_kernel_small(
        const float* __restrict__ scr,
        unsigned short* __restrict__ selmask,
        unsigned long long* __restrict__ keyw,
        unsigned int* __restrict__ cntw) {
    const int L = blockIdx.z, b = blockIdx.y;
    const int wl2 = 7 - L;
    const int w = 1 << wl2;
    const int P = 1 << (2 * wl2);
    const int k = 4 << L;
    const int p = blockIdx.x * 256 + threadIdx.x;
    if (p >= P) return;
    const int y = p >> wl2, x = p & (w - 1);
    const int r0 = k * y + (k >> 1) - 1;
    const int c0 = k * x + (k >> 1) - 1;
    const float* Sb = scr + (size_t)b * NI * 262144;
    const int lane = threadIdx.x & 63, wvq = threadIdx.x >> 6;

    __shared__ unsigned long long skey[4][NI];
    __shared__ unsigned int scnt[4][NI];

    unsigned int mask = 0;
#pragma unroll
    for (int i = 0; i < NI; ++i) {
        const float* Si = Sb + (size_t)i * 262144 + r0 * 512 + c0;
        float v;
        if (k == 4) {
            const float4 t0 = *(const float4*)(Si - 1);
            const float4 t1 = *(const float4*)(Si - 1 + 512);
            v = (t0.y + t0.z) + (t1.y + t1.z);
        } else {
            v = (Si[0] + Si[1]) + (Si[512] + Si[513]);
        }
        const bool sel = v > 2.0f;
        mask |= sel ? (1u << i) : 0u;
        unsigned long long key = ((unsigned long long)ordered_bits(v) << 32)
                               | (unsigned long long)(0xFFFFFFFFu - (unsigned int)p);
#pragma unroll
        for (int off = 32; off > 0; off >>= 1) {
            unsigned long long o = shfl_down_u64(key, off);
            if (o > key) key = o;
        }
        unsigned long long bal = __ballot(sel);
        if (lane == 0) {
            skey[wvq][i] = key;
            scnt[wvq][i] = (unsigned int)__popcll(bal);
        }
    }
    selmask[(size_t)b * PTOT + level_off(L) + p] = (unsigned short)mask;

    __syncthreads();
    if (threadIdx.x < NI) {
        const int i = threadIdx.x;
        unsigned long long kk = skey[0][i];
        unsigned int cc = scnt[0][i];
#pragma unroll
        for (int wq = 1; wq < 4; ++wq) {
            if (skey[wq][i] > kk) kk = skey[wq][i];
            cc += scnt[wq][i];
        }
        atomicMax(&keyw[(L * NB + b) * NI + i], kk);
        atomicAdd(&cntw[(L * NB + b) * NI + i], cc);
    }
}

__global__ void key_to_idx(const unsigned long long* __restrict__ keyw,
                           unsigned int* __restrict__ amaxp) {
    const int g = blockIdx.x * 64 + threadIdx.x;
    if (g < 512) amaxp[g] = 0xFFFFFFFFu - (unsigned int)(keyw[g] & 0xFFFFFFFFull);
}

__global__ __launch_bounds__(256) void pool_kernel(
        const float* __restrict__ f0, const float* __restrict__ f1,
        const float* __restrict__ f2, const float* __restrict__ f3,
        const unsigned short* __restrict__ selmask,
        float* __restrict__ sw) {
    const int L = blockIdx.z, b = blockIdx.y;
    const int wl2 = 7 - L;
    const int P = 1 << (2 * wl2);
    const int lane = threadIdx.x & 63, wvq = threadIdx.x >> 6;
    const int c = blockIdx.x * 4 + wvq;
    const float* fL = (L == 0) ? f0 : (L == 1) ? f1 : (L == 2) ? f2 : f3;
    const float4* frow = (const float4*)(fL + (size_t)(b * NC + c) * P);
    const ushort4* srow = (const ushort4*)(selmask + (size_t)b * PTOT + level_off(L));

    float acc[NI];
#pragma unroll
    for (int i = 0; i < NI; ++i) acc[i] = 0.0f;

    const int iters = P >> 8;
    for (int it = 0; it < iters; ++it) {
        const int e = it * 64 + lane;
        const float4 fv = frow[e];
        const ushort4 mv = srow[e];
        const float fs[4] = {fv.x, fv.y, fv.z, fv.w};
        const unsigned int ms[4] = {mv.x, mv.y, mv.z, mv.w};
#pragma unroll
        for (int q = 0; q < 4; ++q)
#pragma unroll
            for (int i = 0; i < NI; ++i)
                acc[i] = fmaf((float)((ms[q] >> i) & 1u), fs[q], acc[i]);
    }

#pragma unroll
    for (int i = 0; i < NI; ++i) {
        float a = acc[i];
#pragma unroll
        for (int off = 32; off > 0; off >>= 1) a += __shfl_down(a, off, 64);
        if (lane == 0) sw[((size_t)(L * NB + b) * NI + i) * NC + c] = a;
    }
}

// ---------------------------------------------------------------------------
// Kernel C: out[b][i][c] = 0.25 * sum_L (cnt>0 ? s/cnt : f[b][c][argmax])
// ---------------------------------------------------------------------------
__global__ __launch_bounds__(256) void final_kernel(
        const float* __restrict__ f0, const float* __restrict__ f1,
        const float* __restrict__ f2, const float* __restrict__ f3,
        const float* __restrict__ sw,
        const unsigned int* __restrict__ cntw,
        const unsigned int* __restrict__ amaxp,
        float* __restrict__ out) {
    const int nidx = blockIdx.x * 256 + threadIdx.x;   // 32768 total
    const int c = nidx & 255;
    const int bi = nidx >> 8;
    const int i = bi & (NI - 1);
    const int b = bi >> 4;
    float acc = 0.0f;
#pragma unroll
    for (int L = 0; L < 4; ++L) {
        const int g = (L * NB + b) * NI + i;
        const unsigned int cc = cntw[g];
        if (cc > 0) {
            acc += sw[(size_t)g * NC + c] / (float)cc;
        } else {
            const unsigned int p = amaxp[g];
            const float* fL = (L == 0) ? f0 : (L == 1) ? f1 : (L == 2) ? f2 : f3;
            const int P = 16384 >> (2 * L);
            acc += fL[(size_t)(b * NC + c) * P + p];
        }
    }
    out[nidx] = acc * 0.25f;
}

extern "C" void kernel_launch(void* const* d_in, const int* in_sizes, int n_in,
                              void* d_out, int out_size, void* d_ws, size_t ws_size,
                              hipStream_t stream) {
    (void)in_sizes; (void)n_in; (void)out_size;
    const float* f0  = (const float*)d_in[0];   // (8,256,128,128)
    const float* f1  = (const float*)d_in[1];   // (8,256,64,64)
    const float* f2  = (const float*)d_in[2];   // (8,256,32,32)
    const float* f3  = (const float*)d_in[3];   // (8,256,16,16)
    const float* scr = (const float*)d_in[4];   // (8,16,512,512)
    float* out = (float*)d_out;                 // (8,16,256) fp32

    char* ws = (char*)d_ws;

    const size_t VV_SZ   = (size_t)NB * NI * PTOT * 4;      // 11,141,120
    const size_t SW_SZ   = (size_t)4 * NB * NI * NC * 4;    //    524,288
    const size_t SEL_SZ  = (size_t)NB * PTOT * 2;           //    348,160
    const size_t CNT_SZ  = 512 * 4;
    const size_t IDX_SZ  = 512 * 4;
    const size_t KEY_SZ  = 512 * 8;

    if (ws_size >= VV_SZ + SW_SZ + SEL_SZ + CNT_SZ + IDX_SZ) {
        // ---- fast path ----
        float*          vvw  = (float*)ws;
        float*          sww  = (float*)(ws + VV_SZ);
        unsigned short* selm = (unsigned short*)(ws + VV_SZ + SW_SZ);
        unsigned int*   cntw = (unsigned int*)(ws + VV_SZ + SW_SZ + SEL_SZ);
        unsigned int*   idxw = (unsigned int*)(ws + VV_SZ + SW_SZ + SEL_SZ + CNT_SZ);

        hipMemsetAsync(sww, 0, SW_SZ, stream);   // pool_mfma accumulates into sw

        dim3 gA(256, NB, 4);
        mask_kernel<<<gA, 256, 0, stream>>>(scr, selm, vvw);

        argmax_kernel<<<512, 256, 0, stream>>>(vvw, idxw, cntw);

        dim3 gB(32, NB, 4);                      // 4 c-tiles x 8 K-splits
        pool_mfma<<<gB, 256, 0, stream>>>(f0, f1, f2, f3, selm, sww);

        final_kernel<<<128, 256, 0, stream>>>(f0, f1, f2, f3, sww, cntw, idxw, out);
    } else {
        // ---- fallback: small workspace ----
        float*              sww  = (float*)ws;
        unsigned short*     selm = (unsigned short*)(ws + SW_SZ);
        unsigned int*       cntw = (unsigned int*)(ws + SW_SZ + SEL_SZ);
        unsigned int*       idxw = (unsigned int*)(ws + SW_SZ + SEL_SZ + CNT_SZ);
        unsigned long long* keyw = (unsigned long long*)(ws + SW_SZ + SEL_SZ + CNT_SZ + IDX_SZ);

        hipMemsetAsync(cntw, 0, CNT_SZ + IDX_SZ + KEY_SZ, stream);

        dim3 gA(64, NB, 4);
        mask_kernel_small<<<gA, 256, 0, stream>>>(scr, selm, keyw, cntw);
        key_to_idx<<<8, 64, 0, stream>>>(keyw, idxw);

        dim3 gB(NC / 4, NB, 4);
        pool_kernel<<<gB, 256, 0, stream>>>(f0, f1, f2, f3, selm, sww);

        final_kernel<<<128, 256, 0, stream>>>(f0, f1, f2, f3, sww, cntw, idxw, out);
    }
}